// Round 8
// baseline (772.893 us; speedup 1.0000x reference)
//
#include <hip/hip_runtime.h>
#include <hip/hip_bf16.h>

// Swin block: B=64, H=W=56, C=128, WS=7, SHIFT=3, NH=4, hd=32, hidden=512
// Round 8: (a) force wpc<=1024 so each chunk's inter-kernel buffers (~120MB)
// are L3-resident (single-chunk 480MB working set was streaming HBM at 2.2TB/s);
// (b) mlp_fused v2: fc1+GELU+fc2 in one kernel with the PROVEN staging pattern
// (LDS-staged weight chunks + register prefetch under MFMA, hidden tile in LDS
// only, A-frags in registers) - kills the 410MB hidden round-trip. R5's fused
// failure was weight-direct L2 loads serialized against barriers; fixed here.
// ln_qkv / attn / proj_ln unchanged from R7 (proven). Numerics bit-identical.
// ws: [0,64K) btab | 480K weight planes | bufQK | bufV | bufO | bufL.

#define NWIN 4096
#define HB 7440    // attn per-head LDS shorts (8 banks mod 32)
#define KOFF 2568  // K section offset (4 banks mod 32)
#define VOFF 5136  // V^T section offset

typedef __attribute__((ext_vector_type(8))) short s8v;
typedef __attribute__((ext_vector_type(4))) float f4v;

__device__ __forceinline__ void split2(float v, unsigned short& h, unsigned short& l) {
    unsigned int b = __float_as_uint(v);
    h = (unsigned short)(b >> 16);                       // truncated hi
    float hf = __uint_as_float(b & 0xFFFF0000u);
    __hip_bfloat16 lo = __float2bfloat16(v - hf);        // exact residual, RNE
    l = *reinterpret_cast<unsigned short*>(&lo);
}
__device__ __forceinline__ unsigned short bfr(float v) {  // RNE bf16 bits
    __hip_bfloat16 h = __float2bfloat16(v);
    return *reinterpret_cast<unsigned short*>(&h);
}

// ---------------- weight prep (once) ----------------
// plane offsets (shorts): qkvWh 0 (49152), qkvWl 49152, outWr 98304 (16384, RNE),
//                         w1r 114688 (65536, RNE), w2r 180224 (65536, RNE)
__global__ __launch_bounds__(256) void presplit_kernel(
    const float* __restrict__ qkvw, const float* __restrict__ outw,
    const float* __restrict__ w1, const float* __restrict__ w2,
    unsigned short* __restrict__ P)
{
    int i = blockIdx.x * 256 + threadIdx.x;
    if (i >= 196608) return;
    if (i < 49152) {
        float v = qkvw[i];
        if (i < 16384) v *= 0.17677669529663687f;   // fold 1/sqrt(32) into Q rows
        unsigned short h, l; split2(v, h, l);
        P[i] = h; P[49152 + i] = l;
    } else if (i < 65536) {
        int j = i - 49152;
        P[98304 + j] = bfr(outw[j]);                // single-plane RNE
    } else if (i < 131072) {
        int j = i - 65536;
        P[114688 + j] = bfr(w1[j]);
    } else {
        int j = i - 131072;
        P[180224 + j] = bfr(w2[j]);
    }
}

// ---------------- fused LN1 + QKV GEMM (unchanged from R7) ----------------
__global__ __launch_bounds__(256) void ln_qkv(
    const float* __restrict__ x,
    const float* __restrict__ g, const float* __restrict__ bta,
    const unsigned short* __restrict__ W,     // qkvWh@0, qkvWl@49152
    const float* __restrict__ bias,
    unsigned short* __restrict__ OutQK, unsigned short* __restrict__ OutV,
    int M, int tbase)
{
    __shared__ __align__(16) unsigned short Ah[64 * 40];
    __shared__ __align__(16) unsigned short Al[64 * 40];
    __shared__ __align__(16) unsigned short Wh[64 * 40];
    __shared__ __align__(16) unsigned short Wl[64 * 40];
    int tid = threadIdx.x;
    int m0 = blockIdx.y * 64, n0 = blockIdx.x * 64;
    int sr = tid >> 2, sq = (tid & 3) * 8;
    int ar = m0 + sr; if (ar >= M) ar = M - 1;
    int t = tbase + ar;
    int n = t / 49, l = t - n * 49;
    int b = n >> 6, wh_ = (n >> 3) & 7, ww = n & 7;
    int i = l / 7, j = l - i * 7;
    int sh = (wh_ * 7 + i + 53) % 56, sw = (ww * 7 + j + 53) % 56;
    const float* ip = x + (size_t)((b * 56 + sh) * 56 + sw) * 128;

    float v[4][8];
    float s = 0.f, q2 = 0.f;
    #pragma unroll
    for (int kc = 0; kc < 4; ++kc) {
        float4 a = *reinterpret_cast<const float4*>(ip + kc * 32 + sq);
        float4 c = *reinterpret_cast<const float4*>(ip + kc * 32 + sq + 4);
        v[kc][0] = a.x; v[kc][1] = a.y; v[kc][2] = a.z; v[kc][3] = a.w;
        v[kc][4] = c.x; v[kc][5] = c.y; v[kc][6] = c.z; v[kc][7] = c.w;
        #pragma unroll
        for (int e = 0; e < 8; ++e) { s += v[kc][e]; q2 += v[kc][e] * v[kc][e]; }
    }
    s  += __shfl_xor(s, 1);  s  += __shfl_xor(s, 2);
    q2 += __shfl_xor(q2, 1); q2 += __shfl_xor(q2, 2);
    float mean = s * (1.0f / 128.0f);
    float var  = q2 * (1.0f / 128.0f) - mean * mean;
    float rstd = rsqrtf(var + 1e-5f);
    unsigned short ah[4][8], al[4][8];
    #pragma unroll
    for (int kc = 0; kc < 4; ++kc)
        #pragma unroll
        for (int e = 0; e < 8; ++e) {
            int c = kc * 32 + sq + e;
            float r = (v[kc][e] - mean) * rstd * g[c] + bta[c];
            split2(r, ah[kc][e], al[kc][e]);
        }

    int wv = tid >> 6, ln = tid & 63;
    int wm = wv & 1, wn = wv >> 1;
    int fm = ln & 15, fq = ln >> 4;
    const unsigned short* Whg = W;
    const unsigned short* Wlg = W + 49152;
    size_t wrow = (size_t)(n0 + sr) * 128 + sq;
    int so = sr * 40 + sq;
    s8v rwh = *reinterpret_cast<const s8v*>(Whg + wrow);
    s8v rwl = *reinterpret_cast<const s8v*>(Wlg + wrow);

    f4v acc[2][2] = {};
    #pragma unroll
    for (int kc = 0; kc < 4; ++kc) {
        *reinterpret_cast<s8v*>(&Ah[so]) = *reinterpret_cast<const s8v*>(ah[kc]);
        *reinterpret_cast<s8v*>(&Al[so]) = *reinterpret_cast<const s8v*>(al[kc]);
        *reinterpret_cast<s8v*>(&Wh[so]) = rwh;
        *reinterpret_cast<s8v*>(&Wl[so]) = rwl;
        __syncthreads();
        if (kc < 3) {
            rwh = *reinterpret_cast<const s8v*>(Whg + wrow + (kc + 1) * 32);
            rwl = *reinterpret_cast<const s8v*>(Wlg + wrow + (kc + 1) * 32);
        }
        s8v fah[2], fal[2], fbh[2], fbl[2];
        #pragma unroll
        for (int tt = 0; tt < 2; ++tt) {
            int ao = (wm * 32 + tt * 16 + fm) * 40 + fq * 8;
            fah[tt] = *reinterpret_cast<const s8v*>(&Ah[ao]);
            fal[tt] = *reinterpret_cast<const s8v*>(&Al[ao]);
            int bo = (wn * 32 + tt * 16 + fm) * 40 + fq * 8;
            fbh[tt] = *reinterpret_cast<const s8v*>(&Wh[bo]);
            fbl[tt] = *reinterpret_cast<const s8v*>(&Wl[bo]);
        }
        #pragma unroll
        for (int tm = 0; tm < 2; ++tm)
            #pragma unroll
            for (int tn = 0; tn < 2; ++tn) {
                acc[tm][tn] = __builtin_amdgcn_mfma_f32_16x16x32_bf16(fah[tm], fbh[tn], acc[tm][tn], 0, 0, 0);
                acc[tm][tn] = __builtin_amdgcn_mfma_f32_16x16x32_bf16(fah[tm], fbl[tn], acc[tm][tn], 0, 0, 0);
                acc[tm][tn] = __builtin_amdgcn_mfma_f32_16x16x32_bf16(fal[tm], fbh[tn], acc[tm][tn], 0, 0, 0);
            }
        __syncthreads();
    }

    #pragma unroll
    for (int tm = 0; tm < 2; ++tm)
        #pragma unroll
        for (int tn = 0; tn < 2; ++tn) {
            int col = n0 + wn * 32 + tn * 16 + fm;
            float bv = bias[col];
            if (col < 128) bv *= 0.17677669529663687f;
            #pragma unroll
            for (int r = 0; r < 4; ++r) {
                int m = m0 + wm * 32 + tm * 16 + fq * 4 + r;
                if (m >= M) continue;
                float vv = acc[tm][tn][r] + bv;
                if (col < 256) {
                    OutQK[(size_t)m * 256 + col] = bfr(vv);
                } else {
                    int dd = col - 256, hh = dd >> 5, d = dd & 31;
                    int win = m / 49, l2 = m - win * 49;
                    int kp = (l2 & 15) * 4 + (l2 >> 4);   // k' permutation
                    OutV[((size_t)win * 128 + hh * 32 + d) * 64 + kp] = bfr(vv);
                }
            }
        }
}

// ---------------- bias table in MFMA C-layout ----------------
__global__ void bias_tab_kernel(const float* __restrict__ pe, float* __restrict__ tab) {
    int t = threadIdx.x;          // 256 = 4 heads x 64 lanes
    int h = t >> 6, ln = t & 63;
    int g = ln >> 4, c = ln & 15;
    for (int mt = 0; mt < 4; ++mt)
        for (int nt = 0; nt < 4; ++nt)
            for (int r = 0; r < 4; ++r) {
                int l1 = mt * 16 + g * 4 + r, l2 = nt * 16 + c;
                float b = 0.f;
                if (l1 < 49 && l2 < 49) {
                    int i1 = l1 / 7, j1 = l1 % 7, i2 = l2 / 7, j2 = l2 % 7;
                    b = pe[h * 169 + (i1 - i2 + 6) * 13 + (j1 - j2 + 6)];
                }
                tab[((h * 64 + ln) * 16 + mt * 4 + nt) * 4 + r] = b;
            }
}

// ---------------- MFMA attention (conflict-fixed, unchanged) ----------------
__global__ __launch_bounds__(256) void attn_mfma(
    const unsigned short* __restrict__ qk,
    const unsigned short* __restrict__ vt,
    const float* __restrict__ btab,
    unsigned short* __restrict__ oH)
{
    __shared__ __align__(16) unsigned short lds[4 * HB];
    int tid = threadIdx.x;
    int win = blockIdx.x;
    const unsigned short* srcqk = qk + (size_t)win * 49 * 256;
    const unsigned short* srcv  = vt + (size_t)win * 8192;

    for (int idx = tid; idx < 1568; idx += 256) {
        int l2 = idx >> 5, c8 = idx & 31;
        int d8 = c8 * 8;
        s8v v8 = *reinterpret_cast<const s8v*>(srcqk + (size_t)l2 * 256 + d8);
        int sec = d8 >> 7, dd = d8 & 127, hh = dd >> 5, kk = dd & 31;
        *reinterpret_cast<s8v*>(&lds[hh * HB + (sec ? KOFF : 0) + l2 * 40 + kk]) = v8;
    }
    for (int idx = tid; idx < 1024; idx += 256) {
        int row = idx >> 3, j = idx & 7;
        s8v v8 = *reinterpret_cast<const s8v*>(srcv + (size_t)row * 64 + j * 8);
        int hh = row >> 5, d = row & 31;
        *reinterpret_cast<s8v*>(&lds[hh * HB + VOFF + d * 72 + j * 8]) = v8;
    }
    __syncthreads();
    for (int i = tid; i < 1920; i += 256) {
        int hh = i / 480, rem = i % 480, d = rem / 15, j = rem % 15;
        lds[hh * HB + VOFF + d * 72 + (j + 1) * 4 + 3] = 0;
    }
    __syncthreads();

    int h = tid >> 6, ln = tid & 63;
    int fm = ln & 15, fq = ln >> 4;
    int base = h * HB;

    s8v Qf[4], Kf[4];
    #pragma unroll
    for (int t = 0; t < 4; ++t) {
        Qf[t] = *reinterpret_cast<const s8v*>(&lds[base + (t * 16 + fm) * 40 + fq * 8]);
        Kf[t] = *reinterpret_cast<const s8v*>(&lds[base + KOFF + (t * 16 + fm) * 40 + fq * 8]);
    }
    f4v S[4][4] = {};
    #pragma unroll
    for (int mt = 0; mt < 4; ++mt)
        #pragma unroll
        for (int nt = 0; nt < 4; ++nt)
            S[mt][nt] = __builtin_amdgcn_mfma_f32_16x16x32_bf16(Qf[mt], Kf[nt], S[mt][nt], 0, 0, 0);
    #pragma unroll
    for (int mt = 0; mt < 4; ++mt)
        #pragma unroll
        for (int nt = 0; nt < 4; ++nt)
            S[mt][nt] += *reinterpret_cast<const f4v*>(&btab[((h * 64 + ln) * 16 + mt * 4 + nt) * 4]);

    float rcp[16];
    #pragma unroll
    for (int mt = 0; mt < 4; ++mt) {
        #pragma unroll
        for (int r = 0; r < 4; ++r) {
            float v0 = S[mt][0][r], v1 = S[mt][1][r], v2 = S[mt][2][r], v3 = S[mt][3][r];
            if (fm != 0) v3 = -1e30f;
            float mx = fmaxf(fmaxf(v0, v1), fmaxf(v2, v3));
            #pragma unroll
            for (int off = 1; off < 16; off <<= 1) mx = fmaxf(mx, __shfl_xor(mx, off));
            float e0 = __expf(v0 - mx), e1 = __expf(v1 - mx);
            float e2 = __expf(v2 - mx), e3 = __expf(v3 - mx);
            float sm = e0 + e1 + e2 + e3;
            #pragma unroll
            for (int off = 1; off < 16; off <<= 1) sm += __shfl_xor(sm, off);
            rcp[mt * 4 + r] = 1.0f / sm;
            int row = mt * 16 + fq * 4 + r;
            ushort4 pk = { bfr(e0), bfr(e1), bfr(e2), bfr(e3) };  // k' = fm*4 + q16
            *reinterpret_cast<ushort4*>(&lds[base + row * 72 + fm * 4]) = pk;
        }
    }

    f4v O[4][2] = {};
    #pragma unroll
    for (int kt = 0; kt < 2; ++kt) {
        s8v Pf[4], Vf[2];
        #pragma unroll
        for (int mt = 0; mt < 4; ++mt)
            Pf[mt] = *reinterpret_cast<const s8v*>(&lds[base + (mt * 16 + fm) * 72 + kt * 32 + fq * 8]);
        #pragma unroll
        for (int nt = 0; nt < 2; ++nt)
            Vf[nt] = *reinterpret_cast<const s8v*>(&lds[base + VOFF + (nt * 16 + fm) * 72 + kt * 32 + fq * 8]);
        #pragma unroll
        for (int mt = 0; mt < 4; ++mt)
            #pragma unroll
            for (int nt = 0; nt < 2; ++nt)
                O[mt][nt] = __builtin_amdgcn_mfma_f32_16x16x32_bf16(Pf[mt], Vf[nt], O[mt][nt], 0, 0, 0);
    }

    size_t ob = (size_t)win * 49 * 128 + h * 32;
    #pragma unroll
    for (int mt = 0; mt < 4; ++mt)
        #pragma unroll
        for (int r = 0; r < 4; ++r) {
            int row = mt * 16 + fq * 4 + r;
            if (row < 49) {
                float sc = rcp[mt * 4 + r];
                #pragma unroll
                for (int nt = 0; nt < 2; ++nt)
                    oH[ob + (size_t)row * 128 + nt * 16 + fm] = bfr(O[mt][nt][r] * sc);
            }
        }
}

// ---------------- proj + LN2 fused: LDS-staged single-plane W (unchanged) ----------------
__global__ __launch_bounds__(256) void proj_ln(
    const unsigned short* __restrict__ Ag,    // attn out bf16 [M,128]
    const unsigned short* __restrict__ Wg,    // outWr [128,128] RNE bf16
    const float* __restrict__ bias,
    const float* __restrict__ g, const float* __restrict__ bta,
    unsigned short* __restrict__ Out, int M)
{
    __shared__ __align__(16) unsigned short As[64 * 132];
    __shared__ __align__(16) unsigned short Ws[128 * 40];
    __shared__ float red[2][2][64];
    int tid = threadIdx.x;
    int m0 = blockIdx.x * 64;
    for (int c = tid; c < 1024; c += 256) {
        int row = c >> 4, c8 = (c & 15) * 8;
        int ar = m0 + row; if (ar >= M) ar = M - 1;
        *reinterpret_cast<s8v*>(&As[row * 132 + c8]) =
            *reinterpret_cast<const s8v*>(Ag + (size_t)ar * 128 + c8);
    }
    int w0r = tid >> 2, w0c = (tid & 3) * 8;
    int w1r = 64 + w0r;
    s8v rw0 = *reinterpret_cast<const s8v*>(Wg + (size_t)w0r * 128 + w0c);
    s8v rw1 = *reinterpret_cast<const s8v*>(Wg + (size_t)w1r * 128 + w0c);

    int wv = tid >> 6, ln = tid & 63;
    int wm = wv & 1, wn = wv >> 1;
    int fm = ln & 15, fq = ln >> 4;
    f4v acc[2][4] = {};
    for (int kc = 0; kc < 4; ++kc) {
        *reinterpret_cast<s8v*>(&Ws[w0r * 40 + w0c]) = rw0;
        *reinterpret_cast<s8v*>(&Ws[w1r * 40 + w0c]) = rw1;
        __syncthreads();
        if (kc < 3) {
            rw0 = *reinterpret_cast<const s8v*>(Wg + (size_t)w0r * 128 + (kc + 1) * 32 + w0c);
            rw1 = *reinterpret_cast<const s8v*>(Wg + (size_t)w1r * 128 + (kc + 1) * 32 + w0c);
        }
        s8v fa[2], fb[4];
        #pragma unroll
        for (int t = 0; t < 2; ++t)
            fa[t] = *reinterpret_cast<const s8v*>(&As[(wm * 32 + t * 16 + fm) * 132 + kc * 32 + fq * 8]);
        #pragma unroll
        for (int t = 0; t < 4; ++t)
            fb[t] = *reinterpret_cast<const s8v*>(&Ws[(wn * 64 + t * 16 + fm) * 40 + fq * 8]);
        #pragma unroll
        for (int tm = 0; tm < 2; ++tm)
            #pragma unroll
            for (int tn = 0; tn < 4; ++tn)
                acc[tm][tn] = __builtin_amdgcn_mfma_f32_16x16x32_bf16(fa[tm], fb[tn], acc[tm][tn], 0, 0, 0);
        __syncthreads();
    }
    float sumv[2][4], sqv[2][4];
    #pragma unroll
    for (int tm = 0; tm < 2; ++tm)
        #pragma unroll
        for (int r = 0; r < 4; ++r) {
            float s = 0.f, q = 0.f;
            #pragma unroll
            for (int tn = 0; tn < 4; ++tn) {
                float v = acc[tm][tn][r] + bias[wn * 64 + tn * 16 + fm];
                acc[tm][tn][r] = v;
                s += v; q += v * v;
            }
            #pragma unroll
            for (int off = 1; off < 16; off <<= 1) { s += __shfl_xor(s, off); q += __shfl_xor(q, off); }
            sumv[tm][r] = s; sqv[tm][r] = q;
        }
    if (fm == 0) {
        #pragma unroll
        for (int tm = 0; tm < 2; ++tm)
            #pragma unroll
            for (int r = 0; r < 4; ++r) {
                int row = wm * 32 + tm * 16 + fq * 4 + r;
                red[wn][0][row] = sumv[tm][r];
                red[wn][1][row] = sqv[tm][r];
            }
    }
    __syncthreads();
    #pragma unroll
    for (int tm = 0; tm < 2; ++tm)
        #pragma unroll
        for (int r = 0; r < 4; ++r) {
            int row = wm * 32 + tm * 16 + fq * 4 + r;
            int m = m0 + row;
            float s = red[0][0][row] + red[1][0][row];
            float q = red[0][1][row] + red[1][1][row];
            float mean = s * (1.0f / 128.0f);
            float var  = q * (1.0f / 128.0f) - mean * mean;
            float rstd = rsqrtf(var + 1e-5f);
            if (m < M) {
                #pragma unroll
                for (int tn = 0; tn < 4; ++tn) {
                    int nn = wn * 64 + tn * 16 + fm;
                    float o = (acc[tm][tn][r] - mean) * rstd * g[nn] + bta[nn];
                    Out[(size_t)m * 128 + nn] = bfr(o);
                }
            }
        }
}

// ---------------- fused MLP v2: fc1 + GELU + fc2, hidden in LDS only ----------------
// Per 64-row block: A frags in regs (loaded once); per hidden 64-col chunk j:
// stage W1/W2 chunks into LDS (register-prefetched under prior MFMA), fc1 MFMA,
// GELU -> Hs, fc2 MFMA accumulate. 3 barriers/chunk, 24 total. Bit-identical
// rounding chain to separate fc1/fc2 (hidden through bf16 RNE either way).
__global__ __launch_bounds__(256) void mlp_fused(
    const unsigned short* __restrict__ Ag,    // LN2 out bf16 [M,128]
    const unsigned short* __restrict__ W1g,   // w1r [512,128] bf16
    const unsigned short* __restrict__ W2g,   // w2r [128,512] bf16
    const float* __restrict__ b1, const float* __restrict__ b2,
    float* __restrict__ y, int M, int tbase)
{
    __shared__ __align__(16) unsigned short W1s[64 * 136];
    __shared__ __align__(16) unsigned short W2s[128 * 72];
    __shared__ __align__(16) unsigned short Hs[64 * 72];
    int tid = threadIdx.x;
    int m0 = blockIdx.x * 64;
    int wv = tid >> 6, ln = tid & 63;
    int wm = wv & 1, wn = wv >> 1;
    int fm = ln & 15, fq = ln >> 4;

    // A fragments in registers: rows wm*32 + t*16 + fm, k = kk*32 + fq*8 (L3-hot)
    s8v fa[2][4];
    #pragma unroll
    for (int t = 0; t < 2; ++t) {
        int ar = m0 + wm * 32 + t * 16 + fm; if (ar >= M) ar = M - 1;
        #pragma unroll
        for (int kk = 0; kk < 4; ++kk)
            fa[t][kk] = *reinterpret_cast<const s8v*>(Ag + (size_t)ar * 128 + kk * 32 + fq * 8);
    }

    int w1row = tid >> 2, w1q = (tid & 3) * 32;   // W1 chunk: 64 rows x 128 k
    int w2row = tid >> 1, w2q = (tid & 1) * 32;   // W2 chunk: 128 rows x 64 k
    s8v rw1[4], rw2[4];
    #pragma unroll
    for (int e = 0; e < 4; ++e) {
        rw1[e] = *reinterpret_cast<const s8v*>(W1g + (size_t)w1row * 128 + w1q + e * 8);
        rw2[e] = *reinterpret_cast<const s8v*>(W2g + (size_t)w2row * 512 + w2q + e * 8);
    }

    f4v acc2[2][4] = {};
    for (int j = 0; j < 8; ++j) {
        #pragma unroll
        for (int e = 0; e < 4; ++e) {
            *reinterpret_cast<s8v*>(&W1s[w1row * 136 + w1q + e * 8]) = rw1[e];
            *reinterpret_cast<s8v*>(&W2s[w2row * 72  + w2q + e * 8]) = rw2[e];
        }
        __syncthreads();                                   // Ws ready
        if (j < 7) {
            #pragma unroll
            for (int e = 0; e < 4; ++e) {
                rw1[e] = *reinterpret_cast<const s8v*>(W1g + (size_t)((j + 1) * 64 + w1row) * 128 + w1q + e * 8);
                rw2[e] = *reinterpret_cast<const s8v*>(W2g + (size_t)w2row * 512 + (j + 1) * 64 + w2q + e * 8);
            }
        }
        // fc1: 64 rows x 64 hidden cols of chunk j
        f4v acc1[2][2] = {};
        #pragma unroll
        for (int kk = 0; kk < 4; ++kk) {
            s8v fb[2];
            #pragma unroll
            for (int t = 0; t < 2; ++t)
                fb[t] = *reinterpret_cast<const s8v*>(&W1s[(wn * 32 + t * 16 + fm) * 136 + kk * 32 + fq * 8]);
            #pragma unroll
            for (int tm = 0; tm < 2; ++tm)
                #pragma unroll
                for (int tn = 0; tn < 2; ++tn)
                    acc1[tm][tn] = __builtin_amdgcn_mfma_f32_16x16x32_bf16(fa[tm][kk], fb[tn], acc1[tm][tn], 0, 0, 0);
        }
        // GELU + bias -> Hs (bf16 RNE, identical to fc1 standalone)
        #pragma unroll
        for (int tm = 0; tm < 2; ++tm)
            #pragma unroll
            for (int tn = 0; tn < 2; ++tn) {
                int nl = wn * 32 + tn * 16 + fm;
                float bv = b1[j * 64 + nl];
                #pragma unroll
                for (int r = 0; r < 4; ++r) {
                    float v = acc1[tm][tn][r] + bv;
                    v = 0.5f * v * (1.0f + erff(v * 0.70710678118654752f));
                    int mrow = wm * 32 + tm * 16 + fq * 4 + r;
                    Hs[mrow * 72 + nl] = bfr(v);
                }
            }
        __syncthreads();                                   // Hs ready
        // fc2 partial over this k chunk
        #pragma unroll
        for (int kt = 0; kt < 2; ++kt) {
            s8v hf[2], wf[4];
            #pragma unroll
            for (int t = 0; t < 2; ++t)
                hf[t] = *reinterpret_cast<const s8v*>(&Hs[(wm * 32 + t * 16 + fm) * 72 + kt * 32 + fq * 8]);
            #pragma unroll
            for (int tn = 0; tn < 4; ++tn)
                wf[tn] = *reinterpret_cast<const s8v*>(&W2s[(wn * 64 + tn * 16 + fm) * 72 + kt * 32 + fq * 8]);
            #pragma unroll
            for (int tm = 0; tm < 2; ++tm)
                #pragma unroll
                for (int tn = 0; tn < 4; ++tn)
                    acc2[tm][tn] = __builtin_amdgcn_mfma_f32_16x16x32_bf16(hf[tm], wf[tn], acc2[tm][tn], 0, 0, 0);
        }
        __syncthreads();                                   // protect Ws/Hs for next j
    }
    // epilogue: + b2, fp32 scatter to y
    #pragma unroll
    for (int tm = 0; tm < 2; ++tm)
        #pragma unroll
        for (int tn = 0; tn < 4; ++tn) {
            int col = wn * 64 + tn * 16 + fm;
            float bv = b2[col];
            #pragma unroll
            for (int r = 0; r < 4; ++r) {
                int m = m0 + wm * 32 + tm * 16 + fq * 4 + r;
                if (m >= M) continue;
                float v = acc2[tm][tn][r] + bv;
                int t = tbase + m;
                int n = t / 49, l = t - n * 49;
                int b = n >> 6, wh_ = (n >> 3) & 7, ww = n & 7;
                int i = l / 7, jj = l - i * 7;
                size_t orow = (size_t)((b * 56 + wh_ * 7 + i) * 56 + ww * 7 + jj);
                y[orow * 128 + col] = v;
            }
        }
}

extern "C" void kernel_launch(void* const* d_in, const int* in_sizes, int n_in,
                              void* d_out, int out_size, void* d_ws, size_t ws_size,
                              hipStream_t stream) {
    const float* x    = (const float*)d_in[0];
    const float* n1g  = (const float*)d_in[1];
    const float* n1b  = (const float*)d_in[2];
    const float* qkvw = (const float*)d_in[3];
    const float* qkvb = (const float*)d_in[4];
    const float* outw = (const float*)d_in[5];
    const float* outb = (const float*)d_in[6];
    const float* pe   = (const float*)d_in[7];
    const float* n2g  = (const float*)d_in[8];
    const float* n2b  = (const float*)d_in[9];
    const float* w1   = (const float*)d_in[10];
    const float* b1   = (const float*)d_in[11];
    const float* w2   = (const float*)d_in[12];
    const float* b2   = (const float*)d_in[13];
    float* y = (float*)d_out;

    // fixed overhead: 64 KB btab + 480 KB weight planes = 557056 B
    // per-window: QK 25088 + V 16384 + O 12544 + L 12544 = 66560 B
    size_t wpc = NWIN;
    while (wpc > 8 && 557056 + wpc * 66560ULL > ws_size) wpc >>= 1;
    if (wpc > 1024) wpc = 1024;   // keep per-chunk buffer chain L3-resident (~120MB)
    const int nchunks = (int)(NWIN / wpc);
    const size_t rows = wpc * 49;

    char* ws = (char*)d_ws;
    float* btab = (float*)ws;                                    // 64 KB
    unsigned short* wpl = (unsigned short*)(ws + 65536);         // 491520 B of planes
    unsigned short* bufQK = (unsigned short*)(ws + 557056);      // rows*256
    unsigned short* bufV  = bufQK + rows * 256;                  // wpc*8192
    unsigned short* bufO  = bufV + wpc * 8192;                   // rows*128 (attn out)
    unsigned short* bufL  = bufO + rows * 128;                   // rows*128 (LN2 out)
    const int gy = (int)((rows + 63) / 64);

    presplit_kernel<<<768, 256, 0, stream>>>(qkvw, outw, w1, w2, wpl);
    bias_tab_kernel<<<1, 256, 0, stream>>>(pe, btab);

    for (int c = 0; c < nchunks; ++c) {
        int tbase = (int)(c * wpc * 49);
        // fused LN1 + QKV (3-term): x -> QK [rows,256] + V^T [wpc,128,64]
        ln_qkv<<<dim3(6, gy), 256, 0, stream>>>(
            x, n1g, n1b, wpl, qkvb, bufQK, bufV, (int)rows, tbase);
        // attention -> bf16 [rows,128]
        attn_mfma<<<(int)wpc, 256, 0, stream>>>(bufQK, bufV, btab, bufO);
        // proj + LN2 fused -> bf16 [rows,128]
        proj_ln<<<gy, 256, 0, stream>>>(bufO, wpl + 98304, outb, n2g, n2b, bufL, (int)rows);
        // fused MLP: fc1+GELU+fc2, hidden LDS-only -> fp32 scatter to y
        mlp_fused<<<gy, 256, 0, stream>>>(
            bufL, wpl + 114688, wpl + 180224, b1, b2, y, (int)rows, tbase);
    }
}